// Round 1
// baseline (39.286 us; speedup 1.0000x reference)
//
#include <hip/hip_runtime.h>
#include <math.h>

#define BATCH 8192
#define NSTK  4096
#define TPB   256
#define EPT   16          // elements per thread: 256*16 = 4096 = NSTK

#define NEG_BIG (-1.0e30f)
#define LN2f    (0.6931471805599453f)
#define LOG2Ef  (1.4426950408889634f)

// hardware base-2 transcendentals (v_exp_f32 / v_log_f32)
__device__ __forceinline__ float fexp2(float x) { return __builtin_amdgcn_exp2f(x); }
__device__ __forceinline__ float flog2(float x) { return __builtin_amdgcn_logf(x); }

// logsumexp combine in (max, sum-of-2^) representation, base-2 domain
__device__ __forceinline__ void lse_combine(float& m, float& s, float m2, float s2) {
    float M = fmaxf(m, m2);
    s = s * fexp2(m - M) + s2 * fexp2(m2 - M);
    m = M;
}

__global__ __launch_bounds__(TPB) void suffix_lse_rows(const float* __restrict__ f,
                                                       float* __restrict__ row_out) {
    const int row  = blockIdx.x;
    const int tid  = threadIdx.x;
    const int lane = tid & 63;
    const int wave = tid >> 6;

    const float* rowp = f + (size_t)row * NSTK + (size_t)tid * EPT;

    // ---- load 16 contiguous fp32, pre-scale to base-2 domain ----
    float g[EPT];
    const float4* p4 = reinterpret_cast<const float4*>(rowp);
#pragma unroll
    for (int i = 0; i < 4; ++i) {
        float4 v = p4[i];
        g[4 * i + 0] = v.x * LOG2Ef;
        g[4 * i + 1] = v.y * LOG2Ef;
        g[4 * i + 2] = v.z * LOG2Ef;
        g[4 * i + 3] = v.w * LOG2Ef;
    }

    // ---- pass 1: chunk aggregate (max, sum 2^(g-max)) ----
    float cm = g[0];
#pragma unroll
    for (int j = 1; j < EPT; ++j) cm = fmaxf(cm, g[j]);
    float cs = 0.f;
#pragma unroll
    for (int j = 0; j < EPT; ++j) cs += fexp2(g[j] - cm);

    // ---- wave-level inclusive suffix scan (Hillis-Steele, wave=64) ----
    float im = cm, is = cs;
#pragma unroll
    for (int d = 1; d < 64; d <<= 1) {
        float om = __shfl_down(im, d);
        float os = __shfl_down(is, d);
        if (lane + d < 64) lse_combine(im, is, om, os);
    }
    // exclusive within wave
    float em = __shfl_down(im, 1);
    float es = __shfl_down(is, 1);
    if (lane == 63) { em = NEG_BIG; es = 0.f; }

    // ---- cross-wave: per-wave aggregates via LDS ----
    __shared__ float wam[4], was[4];
    if (lane == 0) { wam[wave] = im; was[wave] = is; }   // incl @ lane0 == wave agg
    __syncthreads();
    float Rm = NEG_BIG, Rs = 0.f;                         // aggregate of waves > mine
#pragma unroll
    for (int w = 0; w < 4; ++w)
        if (w > wave) lse_combine(Rm, Rs, wam[w], was[w]);
    // total exclusive-right state for this thread's chunk
    lse_combine(Rm, Rs, em, es);

    // ---- pass 2: right-to-left sweep; running state IS inclusive suffix LSE ----
    float m = Rm, s = Rs;
    float acc = 0.f, sumg = 0.f;
#pragma unroll
    for (int j = EPT - 1; j >= 0; --j) {
        float M = fmaxf(m, g[j]);
        s = s * fexp2(m - M) + fexp2(g[j] - M);
        m = M;
        acc += m + flog2(s);      // suffix_lse (base 2) of element j
        sumg += g[j];
    }
    float part = acc - sumg;      // (Σ suffix_lse2 - Σ g) for this chunk

    // ---- block reduce part ----
#pragma unroll
    for (int d = 32; d > 0; d >>= 1) part += __shfl_down(part, d);
    __shared__ float wsum[4];
    if (lane == 0) wsum[wave] = part;
    __syncthreads();
    if (tid == 0)
        row_out[row] = LN2f * (wsum[0] + wsum[1] + wsum[2] + wsum[3]);
}

__global__ void reduce_mean(const float* __restrict__ row_vals, float* __restrict__ out) {
    const int tid  = threadIdx.x;
    const int lane = tid & 63;
    const int wave = tid >> 6;
    double acc = 0.0;
    for (int i = tid; i < BATCH; i += 256) acc += (double)row_vals[i];
#pragma unroll
    for (int d = 32; d > 0; d >>= 1) acc += __shfl_down(acc, d);
    __shared__ double wsum[4];
    if (lane == 0) wsum[wave] = acc;
    __syncthreads();
    if (tid == 0) {
        double t = wsum[0] + wsum[1] + wsum[2] + wsum[3];
        out[0] = (float)(t / (double)BATCH);
    }
}

extern "C" void kernel_launch(void* const* d_in, const int* in_sizes, int n_in,
                              void* d_out, int out_size, void* d_ws, size_t ws_size,
                              hipStream_t stream) {
    const float* f   = (const float*)d_in[0];
    float*       row = (float*)d_ws;        // BATCH floats = 32 KiB scratch
    float*       out = (float*)d_out;
    suffix_lse_rows<<<BATCH, TPB, 0, stream>>>(f, row);
    reduce_mean<<<1, 256, 0, stream>>>(row, out);
}

// Round 2
// 32.821 us; speedup vs baseline: 1.1970x; 1.1970x over previous
//
#include <hip/hip_runtime.h>
#include <math.h>

#define BATCH 8192
#define NSTK  4096
#define TPB   256
#define EPT   16          // elements per thread: 256*16 = 4096 = NSTK

#define NEG_BIG (-1.0e30f)
#define LN2f    (0.6931471805599453f)
#define LOG2Ef  (1.4426950408889634f)

// hardware base-2 transcendentals (v_exp_f32 / v_log_f32)
__device__ __forceinline__ float fexp2(float x) { return __builtin_amdgcn_exp2f(x); }
__device__ __forceinline__ float flog2(float x) { return __builtin_amdgcn_logf(x); }

// logsumexp combine in (max, sum-of-2^) representation, base-2 domain
__device__ __forceinline__ void lse_combine(float& m, float& s, float m2, float s2) {
    float M = fmaxf(m, m2);
    s = s * fexp2(m - M) + s2 * fexp2(m2 - M);
    m = M;
}

// LDS staging: padded layout word(idx) = idx + 4*(idx>>6)
// -> +16B pad per 64 floats keeps ds_*_b128 16B-aligned;
//    write = 2-way (free), read = 4-way (1.58x), no 32-way serialization.
#define SBUF_WORDS (4096 + 256)

__global__ __launch_bounds__(TPB) void suffix_lse_rows(const float* __restrict__ f,
                                                       float* __restrict__ row_out) {
    __shared__ float sbuf[SBUF_WORDS];
    __shared__ float wam[4], was[4], wsum[4];

    const int row  = blockIdx.x;
    const int tid  = threadIdx.x;
    const int lane = tid & 63;
    const int wave = tid >> 6;

    const float4* p4 = reinterpret_cast<const float4*>(f + (size_t)row * NSTK);

    // ---- coalesced global load -> padded LDS (prescaled to base-2 domain) ----
#pragma unroll
    for (int k = 0; k < 4; ++k) {
        int gidx = (k << 8) + tid;                 // float4 index along row
        float4 v = p4[gidx];
        int w = (gidx << 2) + ((gidx >> 4) << 2);  // idx*4 + 4*((idx*4)>>6)
        *reinterpret_cast<float4*>(&sbuf[w]) =
            make_float4(v.x * LOG2Ef, v.y * LOG2Ef, v.z * LOG2Ef, v.w * LOG2Ef);
    }
    __syncthreads();

    // ---- per-thread contiguous chunk from LDS ----
    float g[EPT];
#pragma unroll
    for (int i = 0; i < 4; ++i) {
        int idx = (tid << 4) + (i << 2);
        int w = idx + ((idx >> 6) << 2);
        float4 v = *reinterpret_cast<const float4*>(&sbuf[w]);
        g[4 * i + 0] = v.x;
        g[4 * i + 1] = v.y;
        g[4 * i + 2] = v.z;
        g[4 * i + 3] = v.w;
    }

    // ---- pass 1: chunk aggregate (max, sum 2^(g-max)) ----
    float cm = g[0];
#pragma unroll
    for (int j = 1; j < EPT; ++j) cm = fmaxf(cm, g[j]);
    float cs = 0.f;
#pragma unroll
    for (int j = 0; j < EPT; ++j) cs += fexp2(g[j] - cm);

    // ---- wave-level inclusive suffix scan (Hillis-Steele, wave=64) ----
    float im = cm, is = cs;
#pragma unroll
    for (int d = 1; d < 64; d <<= 1) {
        float om = __shfl_down(im, d);
        float os = __shfl_down(is, d);
        if (lane + d < 64) lse_combine(im, is, om, os);
    }
    // exclusive within wave
    float em = __shfl_down(im, 1);
    float es = __shfl_down(is, 1);
    if (lane == 63) { em = NEG_BIG; es = 0.f; }

    // ---- cross-wave: per-wave aggregates via LDS ----
    if (lane == 0) { wam[wave] = im; was[wave] = is; }   // incl @ lane0 == wave agg
    __syncthreads();
    float Rm = NEG_BIG, Rs = 0.f;                         // aggregate of waves > mine
#pragma unroll
    for (int w = 0; w < 4; ++w)
        if (w > wave) lse_combine(Rm, Rs, wam[w], was[w]);
    // total exclusive-right state for this thread's chunk
    lse_combine(Rm, Rs, em, es);

    // ---- pass 2: right-to-left sweep, softplus form (2 trans/elem) ----
    // L = inclusive suffix LSE (base-2) as we sweep.
    float L = (Rs == 0.0f) ? -INFINITY : (Rm + flog2(Rs));
    float acc = 0.f, sumg = 0.f;
#pragma unroll
    for (int j = EPT - 1; j >= 0; --j) {
        float d = g[j] - L;                  // +inf at the right boundary: OK
        float t = fexp2(-fabsf(d));          // exp2(-|d|) in [0,1]
        L = fmaxf(g[j], L) + flog2(1.0f + t);
        acc += L;
        sumg += g[j];
    }
    float part = acc - sumg;                 // (Σ suffix_lse2 - Σ g) for this chunk

    // ---- block reduce part ----
#pragma unroll
    for (int d = 32; d > 0; d >>= 1) part += __shfl_down(part, d);
    if (lane == 0) wsum[wave] = part;
    __syncthreads();
    if (tid == 0)
        row_out[row] = LN2f * (wsum[0] + wsum[1] + wsum[2] + wsum[3]);
}

__global__ __launch_bounds__(1024) void reduce_mean(const float* __restrict__ row_vals,
                                                    float* __restrict__ out) {
    const int tid  = threadIdx.x;
    const int lane = tid & 63;
    const int wave = tid >> 6;
    double acc = 0.0;
#pragma unroll
    for (int i = 0; i < BATCH / 1024; ++i) acc += (double)row_vals[tid + i * 1024];
#pragma unroll
    for (int d = 32; d > 0; d >>= 1) acc += __shfl_down(acc, d);
    __shared__ double ws[16];
    if (lane == 0) ws[wave] = acc;
    __syncthreads();
    if (wave == 0) {
        double t = (lane < 16) ? ws[lane] : 0.0;
#pragma unroll
        for (int d = 8; d > 0; d >>= 1) t += __shfl_down(t, d);
        if (lane == 0) out[0] = (float)(t / (double)BATCH);
    }
}

extern "C" void kernel_launch(void* const* d_in, const int* in_sizes, int n_in,
                              void* d_out, int out_size, void* d_ws, size_t ws_size,
                              hipStream_t stream) {
    const float* f   = (const float*)d_in[0];
    float*       row = (float*)d_ws;        // BATCH floats = 32 KiB scratch
    float*       out = (float*)d_out;
    suffix_lse_rows<<<BATCH, TPB, 0, stream>>>(f, row);
    reduce_mean<<<1, 1024, 0, stream>>>(row, out);
}